// Round 1
// baseline (754.831 us; speedup 1.0000x reference)
//
#include <hip/hip_runtime.h>
#include <math.h>

#define NSTEPS 6
#define DT_ 0.2f
#define TXN 64           // threads in x; each owns a float4 (4 cols) -> 256 wide
#define TYN 8            // threads in y (8 waves per block)
#define MR  4            // rows per thread (was 6; cut for VGPR/occupancy)
#define HE  (TYN*MR)     // 32 extended rows per strip
#define INTERIOR (HE-10) // 22 valid interior rows per strip
#define NSTRIP ((HH + INTERIOR - 1)/INTERIOR)  // 12
#define HH 256
#define WW 256

// DPP controls (GFX9 lineage): wave_shr:1 = 0x138 (lane i <- lane i-1),
// wave_shl:1 = 0x130 (lane i <- lane i+1). bound_ctrl=1 -> OOB lanes read 0,
// which IS the conv zero-padding at image left/right edges (wave spans full row).
__device__ __forceinline__ float shl_left(float x){   // returns left-neighbor value
  return __int_as_float(__builtin_amdgcn_update_dpp(
      0, __float_as_int(x), 0x138, 0xF, 0xF, true));
}
__device__ __forceinline__ float shr_right(float x){  // returns right-neighbor value
  return __int_as_float(__builtin_amdgcn_update_dpp(
      0, __float_as_int(x), 0x130, 0xF, 0xF, true));
}

__device__ __forceinline__ void conv_row(const float4 q, float lw, float rx,
                                         float t0, float t1, float t2, float4& acc){
  // output cols c..c+3 get taps t0*in[c-1+k] + t1*in[c+k] + t2*in[c+1+k]
  acc.x = fmaf(t0, lw , fmaf(t1, q.x, fmaf(t2, q.y, acc.x)));
  acc.y = fmaf(t0, q.x, fmaf(t1, q.y, fmaf(t2, q.z, acc.y)));
  acc.z = fmaf(t0, q.y, fmaf(t1, q.z, fmaf(t2, q.w, acc.z)));
  acc.w = fmaf(t0, q.z, fmaf(t1, q.w, fmaf(t2, rx , acc.w)));
}

// min 6 waves/EU -> VGPR cap 85 -> >=3 blocks/CU (24 waves, 75% occ);
// if allocator lands <=64 VGPR we get 4 blocks (LDS 4x32KB=128KB fits 160KB).
__global__ __launch_bounds__(TXN*TYN, 6) void vib6_fused(
    const float* __restrict__ force, const float* __restrict__ cw,
    const float* __restrict__ omega, const float* __restrict__ zeta,
    float* __restrict__ out)
{
  const int tx = threadIdx.x;       // 0..63 == lane id (one wave per ty row)
  const int ty = threadIdx.y;       // 0..7
  const int strip = blockIdx.x;     // 0..NSTRIP-1
  const int plane = blockIdx.y;     // b*64 + c, 0..511
  const int ch = plane & 63;

  // per-channel uniform constants (scalar path: ch is wave-uniform)
  const float om = omega[ch], ze = zeta[ch];
  const float w   = log1pf(expf(om));          // softplus
  const float z   = 1.f/(1.f + expf(-ze));     // sigmoid
  const float w2  = w*w;
  const float aco = 1.f - 2.f*z*w*DT_;         // v' = aco*v + bco*x + DT*(f+inter)
  const float bco = -w2*DT_;
  const float w2h = 0.5f*w2;
  float wdt[9];
  #pragma unroll
  for (int k=0;k<9;++k) wdt[k] = DT_*cw[ch*9+k];   // fold DT into conv taps

  // double-buffered vertical-halo exchange (only top/bottom row of each slab)
  __shared__ float4 topb[2][TYN][TXN];
  __shared__ float4 botb[2][TYN][TXN];

  const int c0 = tx<<2;
  const size_t pbase = (size_t)plane*(HH*WW);

  float4 x[MR], v[MR], F[MR];
  float msk[MR];

  // ---- load force, pre-scale by DT, and do step 1 analytically ----
  #pragma unroll
  for (int i=0;i<MR;++i){
    const int R = ty*MR + i;
    const int g = strip*INTERIOR - 5 + R;   // global row of this ext row
    const bool ok = (g>=0) && (g<HH);
    msk[i] = ok ? 1.f : 0.f;
    float4 f4 = make_float4(0.f,0.f,0.f,0.f);
    if (ok) f4 = *(const float4*)(force + pbase + (size_t)g*WW + c0);
    F[i].x = DT_*f4.x; F[i].y = DT_*f4.y; F[i].z = DT_*f4.z; F[i].w = DT_*f4.w;
    // step 1: conv(x0)=0 -> v1 = DT*f, x1 = DT*v1 (OOB rows: f=0 -> stays 0)
    v[i] = F[i];
    x[i].x = DT_*F[i].x; x[i].y = DT_*F[i].y; x[i].z = DT_*F[i].z; x[i].w = DT_*F[i].w;
  }

  // seed halo buffer for step s=1 (p=1)
  topb[1][ty][tx] = x[0];
  botb[1][ty][tx] = x[MR-1];

  // ---- steps 2..6 ----
  #pragma unroll
  for (int s=1; s<NSTEPS; ++s){
    const int p = s & 1;
    __syncthreads();
    // reads of buf[p^1] (last step) all happened before this barrier, so the
    // finalize-time writes to buf[p^1] below are safe; one barrier per step.
    const float4 zero4 = make_float4(0.f,0.f,0.f,0.f);
    float4 xm1 = (ty>0)      ? botb[p][ty-1][tx] : zero4;  // ext row R0-1
    float4 xp1 = (ty<TYN-1)  ? topb[p][ty+1][tx] : zero4;  // ext row R0+MR

    // rolling accumulators: aP=row r-1, aC=row r, aN=row r+1 while scanning input row r
    float4 aP = make_float4(0,0,0,0), aC = make_float4(0,0,0,0), aN = F[0];

    #pragma unroll
    for (int jj=0; jj<=MR+1; ++jj){
      const int r = jj-1;                              // input ext-local row -1..MR
      const float4 q = (jj==0) ? xm1 : ((jj==MR+1) ? xp1 : x[jj-1]);
      const float lw = shl_left(q.w);    // left neighbor's col (zero at image edge)
      const float rx = shr_right(q.x);   // right neighbor's col (zero at image edge)

      if (r-1 >= 0)            conv_row(q, lw, rx, wdt[6], wdt[7], wdt[8], aP); // di=2
      if (r   >= 0 && r < MR)  conv_row(q, lw, rx, wdt[3], wdt[4], wdt[5], aC); // di=1
      if (r+1 < MR)            conv_row(q, lw, rx, wdt[0], wdt[1], wdt[2], aN); // di=0

      if (r-1 >= 0){           // row r-1 is complete: finalize it
        const int i = r-1;
        v[i].x = fmaf(aco, v[i].x, fmaf(bco, x[i].x, aP.x));
        v[i].y = fmaf(aco, v[i].y, fmaf(bco, x[i].y, aP.y));
        v[i].z = fmaf(aco, v[i].z, fmaf(bco, x[i].z, aP.z));
        v[i].w = fmaf(aco, v[i].w, fmaf(bco, x[i].w, aP.w));
        x[i].x = fmaf(DT_, v[i].x, x[i].x) * msk[i];
        x[i].y = fmaf(DT_, v[i].y, x[i].y) * msk[i];
        x[i].z = fmaf(DT_, v[i].z, x[i].z) * msk[i];
        x[i].w = fmaf(DT_, v[i].w, x[i].w) * msk[i];
        // write next-step halo as soon as the boundary rows finalize:
        // ds_write latency hides under the remaining conv FMAs of this step.
        if (s < NSTEPS-1){
          if (i == 0)    topb[p^1][ty][tx] = x[0];
          if (i == MR-1) botb[p^1][ty][tx] = x[MR-1];
        }
      }
      aP = aC; aC = aN;
      aN = (jj+1 < MR) ? F[jj+1] : make_float4(0,0,0,0);
    }
  }

  // ---- epilogue: out = 0.5 v^2 + 0.5 w^2 x^2 on interior rows ----
  #pragma unroll
  for (int i=0;i<MR;++i){
    const int R = ty*MR + i;
    if (R >= 5 && R < HE-5){
      const int g = strip*INTERIOR + (R-5);
      if (g < HH){
        float4 o;
        o.x = fmaf(0.5f*v[i].x, v[i].x, w2h*x[i].x*x[i].x);
        o.y = fmaf(0.5f*v[i].y, v[i].y, w2h*x[i].y*x[i].y);
        o.z = fmaf(0.5f*v[i].z, v[i].z, w2h*x[i].z*x[i].z);
        o.w = fmaf(0.5f*v[i].w, v[i].w, w2h*x[i].w*x[i].w);
        *(float4*)(out + pbase + (size_t)g*WW + c0) = o;
      }
    }
  }
}

extern "C" void kernel_launch(void* const* d_in, const int* in_sizes, int n_in,
                              void* d_out, int out_size, void* d_ws, size_t ws_size,
                              hipStream_t stream) {
  const float* force = (const float*)d_in[0];   // [8,64,256,256]
  const float* cw    = (const float*)d_in[1];   // [64,1,3,3]
  const float* om    = (const float*)d_in[2];   // [64]
  const float* ze    = (const float*)d_in[3];   // [64]
  float* out = (float*)d_out;                   // [8,64,256,256]
  dim3 grid(NSTRIP, 8*64);
  dim3 block(TXN, TYN);
  hipLaunchKernelGGL(vib6_fused, grid, block, 0, stream, force, cw, om, ze, out);
}

// Round 2
// 666.326 us; speedup vs baseline: 1.1328x; 1.1328x over previous
//
#include <hip/hip_runtime.h>
#include <math.h>

#define NSTEPS 6
#define DT_ 0.2f
#define TXN 64           // threads in x; each owns a float4 (4 cols) -> 256 wide
#define TYN 8            // threads in y (8 waves per block)
#define MR  4            // rows per thread
#define HE  (TYN*MR)     // 32 extended rows per strip
#define INTERIOR (HE-10) // 22 valid interior rows per strip
#define HH 256
#define WW 256
#define NSTRIP ((HH + INTERIOR - 1)/INTERIOR)  // 12

// DPP controls (GFX9 lineage): wave_shr:1 = 0x138 (lane i <- lane i-1),
// wave_shl:1 = 0x130 (lane i <- lane i+1). bound_ctrl=1 -> OOB lanes read 0,
// which IS the conv zero-padding at image left/right edges (wave spans full row).
__device__ __forceinline__ float shl_left(float x){   // returns left-neighbor value
  return __int_as_float(__builtin_amdgcn_update_dpp(
      0, __float_as_int(x), 0x138, 0xF, 0xF, true));
}
__device__ __forceinline__ float shr_right(float x){  // returns right-neighbor value
  return __int_as_float(__builtin_amdgcn_update_dpp(
      0, __float_as_int(x), 0x130, 0xF, 0xF, true));
}

// Force a wave-uniform float into an SGPR. All users below are v_fma/v_mul with
// at most this one scalar operand -> legal, and frees a VGPR per value.
__device__ __forceinline__ float sconst(float x){
  return __int_as_float(__builtin_amdgcn_readfirstlane(__float_as_int(x)));
}

__device__ __forceinline__ void conv_row(const float4 q, float lw, float rx,
                                         float t0, float t1, float t2, float4& acc){
  // output cols c..c+3 get taps t0*in[c-1+k] + t1*in[c+k] + t2*in[c+1+k]
  acc.x = fmaf(t0, lw , fmaf(t1, q.x, fmaf(t2, q.y, acc.x)));
  acc.y = fmaf(t0, q.x, fmaf(t1, q.y, fmaf(t2, q.z, acc.y)));
  acc.z = fmaf(t0, q.y, fmaf(t1, q.z, fmaf(t2, q.w, acc.z)));
  acc.w = fmaf(t0, q.z, fmaf(t1, q.w, fmaf(t2, rx , acc.w)));
}

// 6 waves/EU -> VGPR cap 85 -> 3 blocks/CU (24 waves, 75% occ).
// With the readfirstlane diet the natural VGPR need is ~70, so no spill.
__global__ __launch_bounds__(TXN*TYN, 6) void vib6_fused(
    const float* __restrict__ force, const float* __restrict__ cw,
    const float* __restrict__ omega, const float* __restrict__ zeta,
    float* __restrict__ out)
{
  const int tx = threadIdx.x;       // 0..63 == lane id (one wave per ty row)
  const int ty = threadIdx.y;       // 0..7
  const int strip = blockIdx.x;     // 0..NSTRIP-1
  const int plane = blockIdx.y;     // b*64 + c, 0..511
  const int ch = plane & 63;

  // per-channel uniform constants -> SGPRs via readfirstlane
  const float om = omega[ch], ze = zeta[ch];
  const float w   = log1pf(expf(om));          // softplus
  const float z   = 1.f/(1.f + expf(-ze));     // sigmoid
  const float w2  = w*w;
  const float aco = sconst(1.f - 2.f*z*w*DT_); // v' = aco*v + bco*x + DT*(f+inter)
  const float bco = sconst(-w2*DT_);
  const float w2h = sconst(0.5f*w2);
  float wdt[9];
  #pragma unroll
  for (int k=0;k<9;++k) wdt[k] = sconst(DT_*cw[ch*9+k]);  // DT folded into taps, SGPR

  // double-buffered vertical-halo exchange (only top/bottom row of each slab)
  __shared__ float4 topb[2][TYN][TXN];
  __shared__ float4 botb[2][TYN][TXN];

  const int c0 = tx<<2;
  const size_t pbase = (size_t)plane*(HH*WW);

  float4 x[MR], v[MR], F[MR];
  float msk[MR];   // wave-uniform (depends on ty+strip only) -> SGPRs

  // ---- load force, pre-scale by DT, and do step 1 analytically ----
  #pragma unroll
  for (int i=0;i<MR;++i){
    const int R = ty*MR + i;
    const int g = strip*INTERIOR - 5 + R;   // global row of this ext row
    const bool ok = (g>=0) && (g<HH);
    msk[i] = sconst(ok ? 1.f : 0.f);
    float4 f4 = make_float4(0.f,0.f,0.f,0.f);
    if (ok) f4 = *(const float4*)(force + pbase + (size_t)g*WW + c0);
    F[i].x = DT_*f4.x; F[i].y = DT_*f4.y; F[i].z = DT_*f4.z; F[i].w = DT_*f4.w;
    // step 1: conv(x0)=0 -> v1 = DT*f, x1 = DT*v1 (OOB rows: f=0 -> stays 0)
    v[i] = F[i];
    x[i].x = DT_*F[i].x; x[i].y = DT_*F[i].y; x[i].z = DT_*F[i].z; x[i].w = DT_*F[i].w;
  }

  // seed halo buffer for step s=1 (p=1)
  topb[1][ty][tx] = x[0];
  botb[1][ty][tx] = x[MR-1];

  // ---- steps 2..6 ----
  #pragma unroll
  for (int s=1; s<NSTEPS; ++s){
    const int p = s & 1;
    __syncthreads();
    // reads of buf[p^1] (last step) all happened before this barrier, so the
    // finalize-time writes to buf[p^1] below are safe; one barrier per step.
    const float4 zero4 = make_float4(0.f,0.f,0.f,0.f);
    float4 xm1 = (ty>0)      ? botb[p][ty-1][tx] : zero4;  // ext row R0-1
    float4 xp1 = (ty<TYN-1)  ? topb[p][ty+1][tx] : zero4;  // ext row R0+MR

    // rolling accumulators: aP=row r-1, aC=row r, aN=row r+1 while scanning input row r
    float4 aP = make_float4(0,0,0,0), aC = make_float4(0,0,0,0), aN = F[0];

    #pragma unroll
    for (int jj=0; jj<=MR+1; ++jj){
      const int r = jj-1;                              // input ext-local row -1..MR
      const float4 q = (jj==0) ? xm1 : ((jj==MR+1) ? xp1 : x[jj-1]);
      const float lw = shl_left(q.w);    // left neighbor's col (zero at image edge)
      const float rx = shr_right(q.x);   // right neighbor's col (zero at image edge)

      if (r-1 >= 0)            conv_row(q, lw, rx, wdt[6], wdt[7], wdt[8], aP); // di=2
      if (r   >= 0 && r < MR)  conv_row(q, lw, rx, wdt[3], wdt[4], wdt[5], aC); // di=1
      if (r+1 < MR)            conv_row(q, lw, rx, wdt[0], wdt[1], wdt[2], aN); // di=0

      if (r-1 >= 0){           // row r-1 is complete: finalize it
        const int i = r-1;
        v[i].x = fmaf(aco, v[i].x, fmaf(bco, x[i].x, aP.x));
        v[i].y = fmaf(aco, v[i].y, fmaf(bco, x[i].y, aP.y));
        v[i].z = fmaf(aco, v[i].z, fmaf(bco, x[i].z, aP.z));
        v[i].w = fmaf(aco, v[i].w, fmaf(bco, x[i].w, aP.w));
        x[i].x = fmaf(DT_, v[i].x, x[i].x) * msk[i];
        x[i].y = fmaf(DT_, v[i].y, x[i].y) * msk[i];
        x[i].z = fmaf(DT_, v[i].z, x[i].z) * msk[i];
        x[i].w = fmaf(DT_, v[i].w, x[i].w) * msk[i];
        // write next-step halo as soon as the boundary rows finalize:
        // ds_write latency hides under the remaining conv FMAs of this step.
        if (s < NSTEPS-1){
          if (i == 0)    topb[p^1][ty][tx] = x[0];
          if (i == MR-1) botb[p^1][ty][tx] = x[MR-1];
        }
      }
      aP = aC; aC = aN;
      aN = (jj+1 < MR) ? F[jj+1] : make_float4(0,0,0,0);
    }
  }

  // ---- epilogue: out = 0.5 v^2 + 0.5 w^2 x^2 on interior rows ----
  #pragma unroll
  for (int i=0;i<MR;++i){
    const int R = ty*MR + i;
    if (R >= 5 && R < HE-5){
      const int g = strip*INTERIOR + (R-5);
      if (g < HH){
        float4 o;
        o.x = fmaf(0.5f*v[i].x, v[i].x, w2h*x[i].x*x[i].x);
        o.y = fmaf(0.5f*v[i].y, v[i].y, w2h*x[i].y*x[i].y);
        o.z = fmaf(0.5f*v[i].z, v[i].z, w2h*x[i].z*x[i].z);
        o.w = fmaf(0.5f*v[i].w, v[i].w, w2h*x[i].w*x[i].w);
        *(float4*)(out + pbase + (size_t)g*WW + c0) = o;
      }
    }
  }
}

extern "C" void kernel_launch(void* const* d_in, const int* in_sizes, int n_in,
                              void* d_out, int out_size, void* d_ws, size_t ws_size,
                              hipStream_t stream) {
  const float* force = (const float*)d_in[0];   // [8,64,256,256]
  const float* cw    = (const float*)d_in[1];   // [64,1,3,3]
  const float* om    = (const float*)d_in[2];   // [64]
  const float* ze    = (const float*)d_in[3];   // [64]
  float* out = (float*)d_out;                   // [8,64,256,256]
  dim3 grid(NSTRIP, 8*64);
  dim3 block(TXN, TYN);
  hipLaunchKernelGGL(vib6_fused, grid, block, 0, stream, force, cw, om, ze, out);
}

// Round 3
// 311.946 us; speedup vs baseline: 2.4198x; 2.1360x over previous
//
#include <hip/hip_runtime.h>
#include <math.h>

#define NSTEPS 6
#define DT_ 0.2f
#define TXN 64           // threads in x; each owns a float4 (4 cols) -> 256 wide
#define TYN 8            // threads in y (8 waves per block)
#define MR  6            // rows per thread (round-0 shape; no forced VGPR cap)
#define HE  (TYN*MR)     // 48 extended rows per strip
#define INTERIOR (HE-10) // 38 valid interior rows per strip
#define HH 256
#define WW 256
#define NSTRIP ((HH + INTERIOR - 1)/INTERIOR)  // 7

// DPP controls (GFX9 lineage): wave_shr:1 = 0x138 (lane i <- lane i-1),
// wave_shl:1 = 0x130 (lane i <- lane i+1). bound_ctrl=1 -> OOB lanes read 0,
// which IS the conv zero-padding at image left/right edges (wave spans full row).
__device__ __forceinline__ float shl_left(float x){   // returns left-neighbor value
  return __int_as_float(__builtin_amdgcn_update_dpp(
      0, __float_as_int(x), 0x138, 0xF, 0xF, true));
}
__device__ __forceinline__ float shr_right(float x){  // returns right-neighbor value
  return __int_as_float(__builtin_amdgcn_update_dpp(
      0, __float_as_int(x), 0x130, 0xF, 0xF, true));
}

// Force a wave-uniform float into an SGPR (frees a VGPR; every consumer below
// is a v_fma/v_mul with at most this one scalar operand -> legal encoding).
__device__ __forceinline__ float sconst(float x){
  return __int_as_float(__builtin_amdgcn_readfirstlane(__float_as_int(x)));
}

__device__ __forceinline__ void conv_row(const float4 q, float lw, float rx,
                                         float t0, float t1, float t2, float4& acc){
  // output cols c..c+3 get taps t0*in[c-1+k] + t1*in[c+k] + t2*in[c+1+k]
  acc.x = fmaf(t0, lw , fmaf(t1, q.x, fmaf(t2, q.y, acc.x)));
  acc.y = fmaf(t0, q.x, fmaf(t1, q.y, fmaf(t2, q.z, acc.y)));
  acc.z = fmaf(t0, q.y, fmaf(t1, q.z, fmaf(t2, q.w, acc.z)));
  acc.w = fmaf(t0, q.z, fmaf(t1, q.w, fmaf(t2, rx , acc.w)));
}

// finalize row i: v' = aco*v + bco*x + acc ; x' = (x + DT*v') * msk
#define FIN(i) do{ \
  v[i].x = fmaf(aco, v[i].x, fmaf(bco, x[i].x, acc[i].x)); \
  v[i].y = fmaf(aco, v[i].y, fmaf(bco, x[i].y, acc[i].y)); \
  v[i].z = fmaf(aco, v[i].z, fmaf(bco, x[i].z, acc[i].z)); \
  v[i].w = fmaf(aco, v[i].w, fmaf(bco, x[i].w, acc[i].w)); \
  x[i].x = fmaf(DT_, v[i].x, x[i].x) * msk[i]; \
  x[i].y = fmaf(DT_, v[i].y, x[i].y) * msk[i]; \
  x[i].z = fmaf(DT_, v[i].z, x[i].z) * msk[i]; \
  x[i].w = fmaf(DT_, v[i].w, x[i].w) * msk[i]; \
}while(0)

// NO min-waves clause: forcing it (rounds 1-2) made the allocator spill the
// whole state array to scratch (2.2 GB round-trip). Natural allocation only.
__global__ __launch_bounds__(TXN*TYN) void vib6_fused(
    const float* __restrict__ force, const float* __restrict__ cw,
    const float* __restrict__ omega, const float* __restrict__ zeta,
    float* __restrict__ out)
{
  const int tx = threadIdx.x;       // 0..63 == lane id (one wave per ty row)
  const int ty = threadIdx.y;       // 0..7
  const int strip = blockIdx.x;     // 0..NSTRIP-1
  const int plane = blockIdx.y;     // b*64 + c, 0..511
  const int ch = plane & 63;

  // per-channel uniform constants -> SGPRs via readfirstlane
  const float om = omega[ch], ze = zeta[ch];
  const float w   = log1pf(expf(om));          // softplus
  const float z   = 1.f/(1.f + expf(-ze));     // sigmoid
  const float w2  = w*w;
  const float aco = sconst(1.f - 2.f*z*w*DT_); // v' = aco*v + bco*x + DT*(f+inter)
  const float bco = sconst(-w2*DT_);
  const float w2h = sconst(0.5f*w2);
  float wdt[9];
  #pragma unroll
  for (int k=0;k<9;++k) wdt[k] = sconst(DT_*cw[ch*9+k]);  // DT folded into taps, SGPR

  // double-buffered vertical-halo exchange (only top/bottom row of each slab)
  __shared__ float4 topb[2][TYN][TXN];
  __shared__ float4 botb[2][TYN][TXN];

  const int c0 = tx<<2;
  const size_t pbase = (size_t)plane*(HH*WW);

  float4 x[MR], v[MR], F[MR];
  float msk[MR];   // wave-uniform (ty+strip only) -> SGPRs

  // ---- load force, pre-scale by DT, and do step 1 analytically ----
  #pragma unroll
  for (int i=0;i<MR;++i){
    const int R = ty*MR + i;
    const int g = strip*INTERIOR - 5 + R;   // global row of this ext row
    const bool ok = (g>=0) && (g<HH);
    msk[i] = sconst(ok ? 1.f : 0.f);
    float4 f4 = make_float4(0.f,0.f,0.f,0.f);
    if (ok) f4 = *(const float4*)(force + pbase + (size_t)g*WW + c0);
    F[i].x = DT_*f4.x; F[i].y = DT_*f4.y; F[i].z = DT_*f4.z; F[i].w = DT_*f4.w;
    // step 1: conv(x0)=0 -> v1 = DT*f, x1 = DT*v1 (OOB rows: f=0 -> stays 0)
    v[i] = F[i];
    x[i].x = DT_*F[i].x; x[i].y = DT_*F[i].y; x[i].z = DT_*F[i].z; x[i].w = DT_*F[i].w;
  }

  // seed halo buffer for step s=1 (p=1)
  topb[1][ty][tx] = x[0];
  botb[1][ty][tx] = x[MR-1];

  // ---- steps 2..6 ----
  // Per-step order is chosen to hide the post-barrier LDS latency:
  //   barrier -> issue ds_reads -> 2 register rows of conv (~60 FMA ~ 120cy,
  //   covering the ~120cy LDS latency) -> consume xm1 -> remaining rows ->
  //   consume xp1 last.
  #pragma unroll
  for (int s=1; s<NSTEPS; ++s){
    const int p = s & 1;
    __syncthreads();
    const float4 zero4 = make_float4(0.f,0.f,0.f,0.f);
    float4 xm1 = (ty>0)      ? botb[p][ty-1][tx] : zero4;  // ext row R0-1
    float4 xp1 = (ty<TYN-1)  ? topb[p][ty+1][tx] : zero4;  // ext row R0+MR

    // per-row conv accumulators, seeded with DT*force (all static indices)
    float4 acc[MR];
    #pragma unroll
    for (int i=0;i<MR;++i) acc[i] = F[i];

    // j=0: contributes to rows 0 (t345) and 1 (t012)
    {
      const float4 q = x[0];
      const float lw = shl_left(q.w), rx = shr_right(q.x);
      conv_row(q, lw, rx, wdt[3], wdt[4], wdt[5], acc[0]);
      conv_row(q, lw, rx, wdt[0], wdt[1], wdt[2], acc[1]);
    }
    // j=1: rows 0 (t678), 1 (t345), 2 (t012)
    {
      const float4 q = x[1];
      const float lw = shl_left(q.w), rx = shr_right(q.x);
      conv_row(q, lw, rx, wdt[6], wdt[7], wdt[8], acc[0]);
      conv_row(q, lw, rx, wdt[3], wdt[4], wdt[5], acc[1]);
      conv_row(q, lw, rx, wdt[0], wdt[1], wdt[2], acc[2]);
    }
    // xm1 (input row -1 -> row 0 with t012); LDS read issued ~60 FMAs ago
    {
      const float lw = shl_left(xm1.w), rx = shr_right(xm1.x);
      conv_row(xm1, lw, rx, wdt[0], wdt[1], wdt[2], acc[0]);
      FIN(0);
      if (s < NSTEPS-1) topb[p^1][ty][tx] = x[0];   // next-step halo, hidden early
    }
    // j=2..MR-1: rolling; row j-1 completes here (rows 1..MR-2)
    #pragma unroll
    for (int j=2; j<MR; ++j){
      const float4 q = x[j];
      const float lw = shl_left(q.w), rx = shr_right(q.x);
      conv_row(q, lw, rx, wdt[6], wdt[7], wdt[8], acc[j-1]);
      conv_row(q, lw, rx, wdt[3], wdt[4], wdt[5], acc[j]);
      if (j+1 < MR) conv_row(q, lw, rx, wdt[0], wdt[1], wdt[2], acc[j+1]);
      FIN(j-1);
    }
    // xp1 (input row MR -> row MR-1 with t678), consumed last
    {
      const float lw = shl_left(xp1.w), rx = shr_right(xp1.x);
      conv_row(xp1, lw, rx, wdt[6], wdt[7], wdt[8], acc[MR-1]);
      FIN(MR-1);
      if (s < NSTEPS-1) botb[p^1][ty][tx] = x[MR-1];
    }
  }

  // ---- epilogue: out = 0.5 v^2 + 0.5 w^2 x^2 on interior rows ----
  #pragma unroll
  for (int i=0;i<MR;++i){
    const int R = ty*MR + i;
    if (R >= 5 && R < HE-5){
      const int g = strip*INTERIOR + (R-5);
      if (g < HH){
        float4 o;
        o.x = fmaf(0.5f*v[i].x, v[i].x, w2h*x[i].x*x[i].x);
        o.y = fmaf(0.5f*v[i].y, v[i].y, w2h*x[i].y*x[i].y);
        o.z = fmaf(0.5f*v[i].z, v[i].z, w2h*x[i].z*x[i].z);
        o.w = fmaf(0.5f*v[i].w, v[i].w, w2h*x[i].w*x[i].w);
        *(float4*)(out + pbase + (size_t)g*WW + c0) = o;
      }
    }
  }
}

extern "C" void kernel_launch(void* const* d_in, const int* in_sizes, int n_in,
                              void* d_out, int out_size, void* d_ws, size_t ws_size,
                              hipStream_t stream) {
  const float* force = (const float*)d_in[0];   // [8,64,256,256]
  const float* cw    = (const float*)d_in[1];   // [64,1,3,3]
  const float* om    = (const float*)d_in[2];   // [64]
  const float* ze    = (const float*)d_in[3];   // [64]
  float* out = (float*)d_out;                   // [8,64,256,256]
  dim3 grid(NSTRIP, 8*64);
  dim3 block(TXN, TYN);
  hipLaunchKernelGGL(vib6_fused, grid, block, 0, stream, force, cw, om, ze, out);
}

// Round 4
// 281.316 us; speedup vs baseline: 2.6832x; 1.1089x over previous
//
#include <hip/hip_runtime.h>
#include <math.h>

#define NSTEPS 6
#define DT_ 0.2f
#define TXN 64           // threads in x; each owns a float4 (4 cols) -> 256 wide
#define TYN 8            // threads in y (8 waves per block)
#define MR  4            // rows per thread: per-row state ~16 VGPR -> target <=64 total
#define HE  (TYN*MR)     // 32 extended rows per strip
#define INTERIOR (HE-10) // 22 valid interior rows per strip
#define HH 256
#define WW 256
#define NSTRIP ((HH + INTERIOR - 1)/INTERIOR)  // 12

// DPP controls (GFX9 lineage): wave_shr:1 = 0x138 (lane i <- lane i-1),
// wave_shl:1 = 0x130 (lane i <- lane i+1). bound_ctrl=1 -> OOB lanes read 0,
// which IS the conv zero-padding at image left/right edges (wave spans full row).
__device__ __forceinline__ float shl_left(float x){   // returns left-neighbor value
  return __int_as_float(__builtin_amdgcn_update_dpp(
      0, __float_as_int(x), 0x138, 0xF, 0xF, true));
}
__device__ __forceinline__ float shr_right(float x){  // returns right-neighbor value
  return __int_as_float(__builtin_amdgcn_update_dpp(
      0, __float_as_int(x), 0x130, 0xF, 0xF, true));
}

// Force a wave-uniform float into an SGPR (frees a VGPR; every consumer below
// is a v_fma/v_mul with at most this one scalar operand -> legal encoding).
__device__ __forceinline__ float sconst(float x){
  return __int_as_float(__builtin_amdgcn_readfirstlane(__float_as_int(x)));
}

__device__ __forceinline__ void conv_row(const float4 q, float lw, float rx,
                                         float t0, float t1, float t2, float4& acc){
  // output cols c..c+3 get taps t0*in[c-1+k] + t1*in[c+k] + t2*in[c+1+k]
  acc.x = fmaf(t0, lw , fmaf(t1, q.x, fmaf(t2, q.y, acc.x)));
  acc.y = fmaf(t0, q.x, fmaf(t1, q.y, fmaf(t2, q.z, acc.y)));
  acc.z = fmaf(t0, q.y, fmaf(t1, q.z, fmaf(t2, q.w, acc.z)));
  acc.w = fmaf(t0, q.z, fmaf(t1, q.w, fmaf(t2, rx , acc.w)));
}

// finalize row i: v' = aco*v + bco*x + acc ; x' = (x + DT*v') * msk
#define FIN(i) do{ \
  v[i].x = fmaf(aco, v[i].x, fmaf(bco, x[i].x, acc[i].x)); \
  v[i].y = fmaf(aco, v[i].y, fmaf(bco, x[i].y, acc[i].y)); \
  v[i].z = fmaf(aco, v[i].z, fmaf(bco, x[i].z, acc[i].z)); \
  v[i].w = fmaf(aco, v[i].w, fmaf(bco, x[i].w, acc[i].w)); \
  x[i].x = fmaf(DT_, v[i].x, x[i].x) * msk[i]; \
  x[i].y = fmaf(DT_, v[i].y, x[i].y) * msk[i]; \
  x[i].z = fmaf(DT_, v[i].z, x[i].z) * msk[i]; \
  x[i].w = fmaf(DT_, v[i].w, x[i].w) * msk[i]; \
}while(0)

// NO min-waves clause: forcing it (rounds 1-2) made the allocator spill the
// whole state array to scratch. MR=4 should land <=64 VGPR *naturally*,
// crossing the 64-reg occupancy step (8 waves/SIMD, 4 blocks/CU; LDS 128KB<=160).
__global__ __launch_bounds__(TXN*TYN) void vib6_fused(
    const float* __restrict__ force, const float* __restrict__ cw,
    const float* __restrict__ omega, const float* __restrict__ zeta,
    float* __restrict__ out)
{
  const int tx = threadIdx.x;       // 0..63 == lane id (one wave per ty row)
  const int ty = threadIdx.y;       // 0..7
  const int strip = blockIdx.x;     // 0..NSTRIP-1
  const int plane = blockIdx.y;     // b*64 + c, 0..511
  const int ch = plane & 63;

  // per-channel uniform constants -> SGPRs via readfirstlane
  const float om = omega[ch], ze = zeta[ch];
  const float w   = log1pf(expf(om));          // softplus
  const float z   = 1.f/(1.f + expf(-ze));     // sigmoid
  const float w2  = w*w;
  const float aco = sconst(1.f - 2.f*z*w*DT_); // v' = aco*v + bco*x + DT*(f+inter)
  const float bco = sconst(-w2*DT_);
  const float w2h = sconst(0.5f*w2);
  float wdt[9];
  #pragma unroll
  for (int k=0;k<9;++k) wdt[k] = sconst(DT_*cw[ch*9+k]);  // DT folded into taps, SGPR

  // double-buffered vertical-halo exchange (only top/bottom row of each slab)
  __shared__ float4 topb[2][TYN][TXN];
  __shared__ float4 botb[2][TYN][TXN];

  const int c0 = tx<<2;
  const size_t pbase = (size_t)plane*(HH*WW);

  float4 x[MR], v[MR], F[MR];
  float msk[MR];   // wave-uniform (ty+strip only) -> SGPRs

  // ---- load force, pre-scale by DT, and do step 1 analytically ----
  #pragma unroll
  for (int i=0;i<MR;++i){
    const int R = ty*MR + i;
    const int g = strip*INTERIOR - 5 + R;   // global row of this ext row
    const bool ok = (g>=0) && (g<HH);
    msk[i] = sconst(ok ? 1.f : 0.f);
    float4 f4 = make_float4(0.f,0.f,0.f,0.f);
    if (ok) f4 = *(const float4*)(force + pbase + (size_t)g*WW + c0);
    F[i].x = DT_*f4.x; F[i].y = DT_*f4.y; F[i].z = DT_*f4.z; F[i].w = DT_*f4.w;
    // step 1: conv(x0)=0 -> v1 = DT*f, x1 = DT*v1 (OOB rows: f=0 -> stays 0)
    v[i] = F[i];
    x[i].x = DT_*F[i].x; x[i].y = DT_*F[i].y; x[i].z = DT_*F[i].z; x[i].w = DT_*F[i].w;
  }

  // seed halo buffer for step s=1 (p=1)
  topb[1][ty][tx] = x[0];
  botb[1][ty][tx] = x[MR-1];

  // ---- steps 2..6 ----
  // Per-step order hides the post-barrier LDS latency: 2 register rows of conv
  // (~60 FMA) run before xm1 is consumed; xp1 is consumed last.
  #pragma unroll
  for (int s=1; s<NSTEPS; ++s){
    const int p = s & 1;
    __syncthreads();
    const float4 zero4 = make_float4(0.f,0.f,0.f,0.f);
    float4 xm1 = (ty>0)      ? botb[p][ty-1][tx] : zero4;  // ext row R0-1
    float4 xp1 = (ty<TYN-1)  ? topb[p][ty+1][tx] : zero4;  // ext row R0+MR

    // per-row conv accumulators, seeded with DT*force (all static indices)
    float4 acc[MR];
    #pragma unroll
    for (int i=0;i<MR;++i) acc[i] = F[i];

    // j=0: contributes to rows 0 (t345) and 1 (t012)
    {
      const float4 q = x[0];
      const float lw = shl_left(q.w), rx = shr_right(q.x);
      conv_row(q, lw, rx, wdt[3], wdt[4], wdt[5], acc[0]);
      conv_row(q, lw, rx, wdt[0], wdt[1], wdt[2], acc[1]);
    }
    // j=1: rows 0 (t678), 1 (t345), 2 (t012)
    {
      const float4 q = x[1];
      const float lw = shl_left(q.w), rx = shr_right(q.x);
      conv_row(q, lw, rx, wdt[6], wdt[7], wdt[8], acc[0]);
      conv_row(q, lw, rx, wdt[3], wdt[4], wdt[5], acc[1]);
      conv_row(q, lw, rx, wdt[0], wdt[1], wdt[2], acc[2]);
    }
    // xm1 (input row -1 -> row 0 with t012); LDS read issued ~60 FMAs ago
    {
      const float lw = shl_left(xm1.w), rx = shr_right(xm1.x);
      conv_row(xm1, lw, rx, wdt[0], wdt[1], wdt[2], acc[0]);
      FIN(0);
      if (s < NSTEPS-1) topb[p^1][ty][tx] = x[0];   // next-step halo, hidden early
    }
    // j=2..MR-1: rolling; row j-1 completes here (rows 1..MR-2)
    #pragma unroll
    for (int j=2; j<MR; ++j){
      const float4 q = x[j];
      const float lw = shl_left(q.w), rx = shr_right(q.x);
      conv_row(q, lw, rx, wdt[6], wdt[7], wdt[8], acc[j-1]);
      conv_row(q, lw, rx, wdt[3], wdt[4], wdt[5], acc[j]);
      if (j+1 < MR) conv_row(q, lw, rx, wdt[0], wdt[1], wdt[2], acc[j+1]);
      FIN(j-1);
    }
    // xp1 (input row MR -> row MR-1 with t678), consumed last
    {
      const float lw = shl_left(xp1.w), rx = shr_right(xp1.x);
      conv_row(xp1, lw, rx, wdt[6], wdt[7], wdt[8], acc[MR-1]);
      FIN(MR-1);
      if (s < NSTEPS-1) botb[p^1][ty][tx] = x[MR-1];
    }
  }

  // ---- epilogue: out = 0.5 v^2 + 0.5 w^2 x^2 on interior rows ----
  #pragma unroll
  for (int i=0;i<MR;++i){
    const int R = ty*MR + i;
    if (R >= 5 && R < HE-5){
      const int g = strip*INTERIOR + (R-5);
      if (g < HH){
        float4 o;
        o.x = fmaf(0.5f*v[i].x, v[i].x, w2h*x[i].x*x[i].x);
        o.y = fmaf(0.5f*v[i].y, v[i].y, w2h*x[i].y*x[i].y);
        o.z = fmaf(0.5f*v[i].z, v[i].z, w2h*x[i].z*x[i].z);
        o.w = fmaf(0.5f*v[i].w, v[i].w, w2h*x[i].w*x[i].w);
        *(float4*)(out + pbase + (size_t)g*WW + c0) = o;
      }
    }
  }
}

extern "C" void kernel_launch(void* const* d_in, const int* in_sizes, int n_in,
                              void* d_out, int out_size, void* d_ws, size_t ws_size,
                              hipStream_t stream) {
  const float* force = (const float*)d_in[0];   // [8,64,256,256]
  const float* cw    = (const float*)d_in[1];   // [64,1,3,3]
  const float* om    = (const float*)d_in[2];   // [64]
  const float* ze    = (const float*)d_in[3];   // [64]
  float* out = (float*)d_out;                   // [8,64,256,256]
  dim3 grid(NSTRIP, 8*64);
  dim3 block(TXN, TYN);
  hipLaunchKernelGGL(vib6_fused, grid, block, 0, stream, force, cw, om, ze, out);
}